// Round 8
// baseline (2676.328 us; speedup 1.0000x reference)
//
#include <hip/hip_runtime.h>
#include <hip/hip_fp16.h>

// ---------------------------------------------------------------------------
// 2-layer LSTM (T=512, B=128, H=512) + linear head, persistent-kernel design.
// Round 18: round-10 geometry/fabric + OPERAND-SWAPPED MFMA (barrier-light).
//  - Fabric: EXACT round-10 flavor (proven fastest r7/r10/r17): consumer-line
//    flags, 48 parallel RMW release, single-line polls, agent-scope 8B ring
//    atomics, sc0sc1 lda16 (with r17's "=&v" early-clobber fix).
//  - NEW: mfma(W_frag, h_frag) instead of mfma(h_frag, W_frag). Fragment
//    symmetry (A's M and B's N both on lane&15) means packed weights and
//    lda16 loads are unchanged; the OUTPUT becomes gates^T: each lane holds
//    1 batch-row x 4 consecutive h-cols -> direct aligned 8B ring store.
//    Deletes the LDS transpose tile + 2 barriers (L1) / 2 of 3 barriers (L2).
//  - x @ W_ih1 (K=5) via one zero-padded MFMA per gate (k>=5 zeroed).
//  - Drain/release: per-wave vmcnt(0) + monotonic LDS counter; last wave
//    fires the 48-RMW release. L2: kh0/kh1 handshake via per-wave LDS
//    counters + double-buffered pbase -> kh0 prefetches next h1 under kh1's
//    critical tail. Zero __syncthreads in both steady-state loops.
//  - All spins bounded (verify-fail, not hang).
// ---------------------------------------------------------------------------

#define HDIM   512
#define TSTEPS 512
#define BATCH  128
#define DIN    5
#define NGRP   4
#define MGRP   32
#define NB1    16
#define NB2    32
#define RING   16
#define SPIN_CAP 16384

#define OFF_W1 0u            // packed layer1 weights: 16 blocks * 128KB = 2MB
#define OFF_W2 2097152u      // packed layer2 weights: 32 blocks * 128KB = 4MB
#define OFF_H1 6291456u      // h1 ring: 4 * 16 * 32 * 512 fp16 = 2MB
#define OFF_H2 8388608u      // h2 ring: 4 * 2 * 32 * 512 fp16 = 256KB
#define OFF_F1 8650752u      // flags1: 4 grp * 48 consumers * 128B
#define OFF_F2 8675328u      // flags2: 4 grp * 48 consumers * 128B
#define WS_END 8699904u
// flags1 consumer c: 0..15 = L1 block j ; 16..47 = L2 block j (kh0/h1)
// flags2 consumer c: 0..31 = L2 block j (kh1/h2) ; 32..47 = L1 back-pressure

typedef _Float16 half8 __attribute__((ext_vector_type(8)));
typedef float    floatx4 __attribute__((ext_vector_type(4)));
typedef unsigned long long u64;

__device__ __forceinline__ float sigf(float v) { return 1.0f / (1.0f + __expf(-v)); }

__device__ __forceinline__ half8 as_h8(uint4 u) {
  union { uint4 u; half8 h; } c; c.u = u; return c.h;
}
__device__ __forceinline__ void ring_st8(_Float16* p, u64 v) {
  __hip_atomic_store((u64*)p, v, __ATOMIC_RELAXED, __HIP_MEMORY_SCOPE_AGENT);
}
__device__ __forceinline__ void flag_add(unsigned* p) {
  __hip_atomic_fetch_add(p, 1u, __ATOMIC_RELAXED, __HIP_MEMORY_SCOPE_AGENT);
}
// Round-10 poll: ONE private consumer line; lane i (<n) reads word i. Bounded.
__device__ __forceinline__ void poll_line(const unsigned* line, int n, unsigned tgt,
                                          int lane) {
  for (int it = 0; it < SPIN_CAP; ++it) {
    unsigned v = tgt;
    if (lane < n)
      v = __hip_atomic_load(line + lane, __ATOMIC_RELAXED, __HIP_MEMORY_SCOPE_AGENT);
    if (__all((int)(v >= tgt))) break;
  }
  __asm__ __volatile__("" ::: "memory");
}
// LDS counter helpers (workgroup scope).
__device__ __forceinline__ unsigned lds_add(unsigned* p) {
  return __hip_atomic_fetch_add(p, 1u, __ATOMIC_RELAXED, __HIP_MEMORY_SCOPE_WORKGROUP);
}
__device__ __forceinline__ unsigned lds_ld(const unsigned* p) {
  return __hip_atomic_load(p, __ATOMIC_RELAXED, __HIP_MEMORY_SCOPE_WORKGROUP);
}
__device__ __forceinline__ void lds_wait2(const unsigned* a, const unsigned* b,
                                          unsigned tgt) {
  for (int it = 0; it < SPIN_CAP; ++it)
    if (lds_ld(a) >= tgt && lds_ld(b) >= tgt) break;
  __asm__ __volatile__("" ::: "memory");
}
// 16 pipelined 16B agent-coherent loads, ONE waitcnt; "=&v" (r17 fix).
__device__ __forceinline__ void lda16(const _Float16* p, uint4* a) {
  asm volatile(
      "global_load_dwordx4 %0, %16, off sc0 sc1\n\t"
      "global_load_dwordx4 %1, %16, off offset:64 sc0 sc1\n\t"
      "global_load_dwordx4 %2, %16, off offset:128 sc0 sc1\n\t"
      "global_load_dwordx4 %3, %16, off offset:192 sc0 sc1\n\t"
      "global_load_dwordx4 %4, %16, off offset:256 sc0 sc1\n\t"
      "global_load_dwordx4 %5, %16, off offset:320 sc0 sc1\n\t"
      "global_load_dwordx4 %6, %16, off offset:384 sc0 sc1\n\t"
      "global_load_dwordx4 %7, %16, off offset:448 sc0 sc1\n\t"
      "global_load_dwordx4 %8, %16, off offset:512 sc0 sc1\n\t"
      "global_load_dwordx4 %9, %16, off offset:576 sc0 sc1\n\t"
      "global_load_dwordx4 %10, %16, off offset:640 sc0 sc1\n\t"
      "global_load_dwordx4 %11, %16, off offset:704 sc0 sc1\n\t"
      "global_load_dwordx4 %12, %16, off offset:768 sc0 sc1\n\t"
      "global_load_dwordx4 %13, %16, off offset:832 sc0 sc1\n\t"
      "global_load_dwordx4 %14, %16, off offset:896 sc0 sc1\n\t"
      "global_load_dwordx4 %15, %16, off offset:960 sc0 sc1\n\t"
      "s_waitcnt vmcnt(0)"
      : "=&v"(a[0]), "=&v"(a[1]), "=&v"(a[2]), "=&v"(a[3]),
        "=&v"(a[4]), "=&v"(a[5]), "=&v"(a[6]), "=&v"(a[7]),
        "=&v"(a[8]), "=&v"(a[9]), "=&v"(a[10]), "=&v"(a[11]),
        "=&v"(a[12]), "=&v"(a[13]), "=&v"(a[14]), "=&v"(a[15])
      : "v"(p)
      : "memory");
}

// ---------------------------------------------------------------------------
extern "C" __global__ void init_kernel(char* __restrict__ ws, float* __restrict__ out,
                                       const float* __restrict__ blin) {
  unsigned tid = blockIdx.x * 256u + threadIdx.x;
  unsigned nz = (WS_END - OFF_H1) / 16u;
  if (tid < nz) ((uint4*)(ws + OFF_H1))[tid] = make_uint4(0, 0, 0, 0);
  if (tid < (unsigned)(BATCH * TSTEPS)) out[tid] = blin[0];
}

// Pack fp32 weights -> fp16 MFMA fragment layout (IDENTICAL to round 10:
// fragment symmetry means the same bytes serve as the A operand).
extern "C" __global__ void pack_kernel(const float* __restrict__ Whh1,
                                       const float* __restrict__ Wih2,
                                       const float* __restrict__ Whh2,
                                       char* __restrict__ ws) {
  unsigned tid = blockIdx.x * 256u + threadIdx.x;
  const float* src;
  char* dst;
  if (tid < 131072u) {
    unsigned lane = tid & 63u, ks = (tid >> 6) & 15u, gg = (tid >> 10) & 3u,
             h = (tid >> 12) & 1u, j = tid >> 13;
    unsigned cg = j * 32u + h * 16u + (lane & 15u);
    unsigned row = gg * 512u + cg;
    unsigned k0 = ks * 32u + (lane >> 4) * 8u;
    src = Whh1 + (size_t)row * 512u + k0;
    dst = ws + OFF_W1 + (size_t)tid * 16u;
  } else {
    unsigned t2 = tid - 131072u;
    if (t2 >= 262144u) return;
    unsigned lane = t2 & 63u, ksl = (t2 >> 6) & 15u, gg = (t2 >> 10) & 3u,
             kh = (t2 >> 12) & 1u, j = t2 >> 13;
    unsigned cg = j * 16u + (lane & 15u);
    unsigned row = gg * 512u + cg;
    unsigned kp = kh * 512u + ksl * 32u + (lane >> 4) * 8u;
    src = (kp < 512u) ? (Wih2 + (size_t)row * 512u + kp)
                      : (Whh2 + (size_t)row * 512u + (kp - 512u));
    dst = ws + OFF_W2 + (size_t)t2 * 16u;
  }
  float4 lo = ((const float4*)src)[0];
  float4 hi = ((const float4*)src)[1];
  _Float16 v[8] = {(_Float16)lo.x, (_Float16)lo.y, (_Float16)lo.z, (_Float16)lo.w,
                   (_Float16)hi.x, (_Float16)hi.y, (_Float16)hi.z, (_Float16)hi.w};
  *(uint4*)dst = *(const uint4*)v;
}

// ---------------------------------------------------------------------------
extern "C" __global__ __launch_bounds__(256, 1) void lstm_persist(
    const float* __restrict__ x,
    const float* __restrict__ Wih1,
    const float* __restrict__ bih1, const float* __restrict__ bhh1,
    const float* __restrict__ bih2, const float* __restrict__ bhh2,
    const float* __restrict__ Wlin,
    float* __restrict__ out,
    char* __restrict__ ws) {
  __shared__ char smem[16512];
  // smem[0..16384): pbase double buffer (L2). smem+16384: counters.
  //   cnt[0] = L1 store-count / L2 release-count (monotonic)
  //   cnt[1],cnt[2] = pbase-produced per kh0 wave (mt 0/1)
  //   cnt[3],cnt[4] = pbase-consumed per kh1 wave (mt 0/1)
  unsigned* cnt = (unsigned*)(smem + 16384);

  const int blk = blockIdx.x;
  const int xcd = blk & 7;
  const int slot = blk >> 3;
  const int tid = threadIdx.x;
  const int wave = tid >> 6;
  const int lane = tid & 63;
  const int nlane = lane & 15;
  const int quad = lane >> 4;

  _Float16* h1ring = (_Float16*)(ws + OFF_H1);
  _Float16* h2ring = (_Float16*)(ws + OFF_H2);

  if (xcd >= NGRP) {
    // ------------------------------ layer 1 -------------------------------
    const int g = xcd - NGRP;
    const int j = slot;
    if (j >= NB1) return;
    if (tid < 16) cnt[tid] = 0;
    __syncthreads();  // once, before the loop
    const char* gW = ws + OFF_W1 + (size_t)j * 131072u;

    unsigned* f1g = (unsigned*)(ws + OFF_F1) + (size_t)g * 48 * 32;
    unsigned* f2g = (unsigned*)(ws + OFF_F2) + (size_t)g * 48 * 32;
    const unsigned* myline = f1g + (size_t)j * 32;         // 16 L1 producers
    const unsigned* mybp    = f2g + (size_t)(32 + j) * 32; // 32 L2 producers
    _Float16* ring = h1ring + (size_t)g * (RING * MGRP * HDIM);

    const int mt = wave >> 1;  // batch half (16 rows)
    const int hh = wave & 1;   // column half (16 cols)

    half8 breg[64];  // register-resident W_hh1 fragments (unchanged)
#pragma unroll
    for (int r = 0; r < 64; ++r)
      breg[r] = *(const half8*)(gW + (size_t)((hh * 64 + r) * 64 + lane) * 16);

    // bias per OUTPUT col (quad*4+r); W_ih1 A-fragment per OPERAND col (nlane)
    float bias16[4][4];
    half8 wfrag[4];
#pragma unroll
    for (int gg = 0; gg < 4; ++gg) {
#pragma unroll
      for (int r = 0; r < 4; ++r) {
        int col = j * 32 + hh * 16 + quad * 4 + r;
        int row = gg * 512 + col;
        bias16[gg][r] = bih1[row] + bhh1[row];
      }
      union { _Float16 e[8]; half8 v; } w;
#pragma unroll
      for (int k = 0; k < 8; ++k) w.e[k] = (_Float16)0.0f;
      if (quad == 0) {
        int col = j * 32 + hh * 16 + nlane;
        const float* wp = Wih1 + (size_t)(gg * 512 + col) * DIN;
#pragma unroll
        for (int k = 0; k < DIN; ++k) w.e[k] = (_Float16)wp[k];
      }
      wfrag[gg] = w.v;
    }
    float cstate[4] = {};
    const int xrow = g * MGRP + mt * 16 + nlane;

    for (int t = 0; t < TSTEPS; ++t) {
      // x B-fragment (row = nlane, k<5) — hoisted before polls
      union { _Float16 e[8]; half8 v; } xf;
#pragma unroll
      for (int k = 0; k < 8; ++k) xf.e[k] = (_Float16)0.0f;
      if (quad == 0) {
        const float* xp = x + ((size_t)t * BATCH + xrow) * DIN;
#pragma unroll
        for (int k = 0; k < DIN; ++k) xf.e[k] = (_Float16)xp[k];
      }
      floatx4 acc[4];
#pragma unroll
      for (int gg = 0; gg < 4; ++gg)
        acc[gg] = (floatx4){bias16[gg][0], bias16[gg][1], bias16[gg][2],
                            bias16[gg][3]};
      // acquire peers' h1(t-1); amortized ring back-pressure
      if (t) poll_line(myline, NB1, (unsigned)t, lane);
      if ((t & 7) == 0 && t >= 16) poll_line(mybp, NB2, (unsigned)(t - 8), lane);

      const _Float16* ap =
          ring + (size_t)((t + RING - 1) & (RING - 1)) * (MGRP * HDIM) +
          mt * 16 * HDIM + nlane * HDIM + quad * 8;
      uint4 areg[16];
      lda16(ap, areg);

      // x-part: one K-padded MFMA per gate
#pragma unroll
      for (int gg = 0; gg < 4; ++gg)
        acc[gg] = __builtin_amdgcn_mfma_f32_16x16x32_f16(wfrag[gg], xf.v,
                                                         acc[gg], 0, 0, 0);
      // h-part: SWAPPED operands -> gates^T
#pragma unroll
      for (int ks = 0; ks < 16; ++ks) {
        half8 av = as_h8(areg[ks]);
#pragma unroll
        for (int gg = 0; gg < 4; ++gg)
          acc[gg] = __builtin_amdgcn_mfma_f32_16x16x32_f16(breg[gg * 16 + ks], av,
                                                           acc[gg], 0, 0, 0);
      }
      // act: lane holds row=mt*16+nlane, cols j*32+hh*16+quad*4+{0..3}
      union { _Float16 h4[4]; u64 v; } hv;
#pragma unroll
      for (int r = 0; r < 4; ++r) {
        float iv = acc[0][r], fv = acc[1][r], gv = acc[2][r], ov = acc[3][r];
        float cn = sigf(fv) * cstate[r] + sigf(iv) * tanhf(gv);
        float hn = sigf(ov) * tanhf(cn);
        cstate[r] = cn;
        hv.h4[r] = (_Float16)hn;
      }
      // direct 8B ring store (no LDS, no barrier)
      ring_st8(ring + (size_t)(t & (RING - 1)) * (MGRP * HDIM) +
                   (size_t)(mt * 16 + nlane) * HDIM + j * 32 + hh * 16 + quad * 4,
               hv.v);
      asm volatile("s_waitcnt vmcnt(0)" ::: "memory");
      unsigned old = 0;
      if (lane == 0) old = lds_add(cnt);
      old = __shfl(old, 0, 64);
      if ((int)old == 4 * t + 3 && lane < 48)
        flag_add(f1g + (size_t)lane * 32 + j);  // 48-RMW release (round-10)
    }
  } else {
    // ------------------------------ layer 2 -------------------------------
    const int g = xcd;
    const int j = slot;
    if (tid < 16) cnt[tid] = 0;
    __syncthreads();  // once
    const char* gW = ws + OFF_W2 + (size_t)j * 131072u;

    unsigned* f1g = (unsigned*)(ws + OFF_F1) + (size_t)g * 48 * 32;
    unsigned* f2g = (unsigned*)(ws + OFF_F2) + (size_t)g * 48 * 32;
    const unsigned* l_h1 = f1g + (size_t)(16 + j) * 32;  // 16 L1 producers
    const unsigned* l_h2 = f2g + (size_t)j * 32;         // 32 L2 producers
    const _Float16* h1rd = h1ring + (size_t)g * (RING * MGRP * HDIM);
    _Float16* ring2 = h2ring + (size_t)g * (2 * MGRP * HDIM);
    floatx4* pb = (floatx4*)smem;  // [2][8][64] = 16KB double buffer

    const int kh = wave & 1;   // 0 -> W_ih2 . h1(t), 1 -> W_hh2 . h2(t-1)
    const int mt = wave >> 1;  // batch half

    half8 breg[64];
#pragma unroll
    for (int r = 0; r < 64; ++r)
      breg[r] = *(const half8*)(gW + (size_t)((kh * 64 + r) * 64 + lane) * 16);

    float bias16[4][4];
#pragma unroll
    for (int gg = 0; gg < 4; ++gg)
#pragma unroll
      for (int r = 0; r < 4; ++r) {
        int col = j * 16 + quad * 4 + r;
        bias16[gg][r] = bih2[gg * 512 + col] + bhh2[gg * 512 + col];
      }
    float wl4[4];
#pragma unroll
    for (int r = 0; r < 4; ++r) wl4[r] = Wlin[j * 16 + quad * 4 + r];
    float cstate[4] = {};

    if (kh == 0) {
      // producer of ih2-partials; runs AHEAD (h1 ready early, L1 leads)
      for (int t = 0; t < TSTEPS; ++t) {
        poll_line(l_h1, NB1, (unsigned)(t + 1), lane);
        const _Float16* ap = h1rd + (size_t)(t & (RING - 1)) * (MGRP * HDIM) +
                             mt * 16 * HDIM + nlane * HDIM + quad * 8;
        uint4 areg[16];
        lda16(ap, areg);
        floatx4 acc[4];
#pragma unroll
        for (int gg = 0; gg < 4; ++gg)
          acc[gg] = (floatx4){bias16[gg][0], bias16[gg][1], bias16[gg][2],
                              bias16[gg][3]};
#pragma unroll
        for (int ks = 0; ks < 16; ++ks) {
          half8 av = as_h8(areg[ks]);
#pragma unroll
          for (int gg = 0; gg < 4; ++gg)
            acc[gg] = __builtin_amdgcn_mfma_f32_16x16x32_f16(breg[gg * 16 + ks],
                                                             av, acc[gg], 0, 0, 0);
        }
        // wait: kh1 consumed slot (t-2) before overwriting pbase[t&1]
        if (t >= 2) lds_wait2(cnt + 3, cnt + 4, (unsigned)(t - 1));
#pragma unroll
        for (int gg = 0; gg < 4; ++gg)
          pb[(size_t)(t & 1) * 512 + (mt * 4 + gg) * 64 + lane] = acc[gg];
        asm volatile("s_waitcnt lgkmcnt(0)" ::: "memory");
        if (lane == 0) lds_add(cnt + 1 + mt);  // publish pbase[t] (this wave)
      }
    } else {
      // critical h2 recurrence
      for (int t = 0; t < TSTEPS; ++t) {
        if (t) poll_line(l_h2, NB2, (unsigned)t, lane);
        const _Float16* ap = ring2 + (size_t)((t + 1) & 1) * (MGRP * HDIM) +
                             mt * 16 * HDIM + nlane * HDIM + quad * 8;
        uint4 areg[16];
        lda16(ap, areg);
        floatx4 acc[4] = {{0.f, 0.f, 0.f, 0.f},
                          {0.f, 0.f, 0.f, 0.f},
                          {0.f, 0.f, 0.f, 0.f},
                          {0.f, 0.f, 0.f, 0.f}};
#pragma unroll
        for (int ks = 0; ks < 16; ++ks) {
          half8 av = as_h8(areg[ks]);
#pragma unroll
          for (int gg = 0; gg < 4; ++gg)
            acc[gg] = __builtin_amdgcn_mfma_f32_16x16x32_f16(breg[gg * 16 + ks],
                                                             av, acc[gg], 0, 0, 0);
        }
        lds_wait2(cnt + 1, cnt + 2, (unsigned)(t + 1));  // pbase[t] ready
#pragma unroll
        for (int gg = 0; gg < 4; ++gg)
          acc[gg] += pb[(size_t)(t & 1) * 512 + (mt * 4 + gg) * 64 + lane];
        asm volatile("s_waitcnt lgkmcnt(0)" ::: "memory");
        if (lane == 0) lds_add(cnt + 3 + mt);  // mark pbase[t] consumed
        // act: lane holds row=mt*16+nlane, cols j*16+quad*4+{0..3}
        union { _Float16 h4[4]; u64 v; } hv;
        float s = 0.f;
#pragma unroll
        for (int r = 0; r < 4; ++r) {
          float iv = acc[0][r], fv = acc[1][r], gv = acc[2][r], ov = acc[3][r];
          float cn = sigf(fv) * cstate[r] + sigf(iv) * tanhf(gv);
          float hn = sigf(ov) * tanhf(cn);
          cstate[r] = cn;
          hv.h4[r] = (_Float16)hn;
          s += wl4[r] * hn;
        }
        ring_st8(ring2 + (size_t)(t & 1) * (MGRP * HDIM) +
                     (size_t)(mt * 16 + nlane) * HDIM + j * 16 + quad * 4,
                 hv.v);
        asm volatile("s_waitcnt vmcnt(0)" ::: "memory");
        unsigned old = 0;
        if (lane == 0) old = lds_add(cnt);
        old = __shfl(old, 0, 64);
        if ((int)old == 2 * t + 1 && lane < 48)
          flag_add(f2g + (size_t)lane * 32 + j);  // 48-RMW release
        // linear head: off the critical path
        s += __shfl_xor(s, 16, 64);
        s += __shfl_xor(s, 32, 64);
        if (quad == 0) {
          int b = g * MGRP + mt * 16 + nlane;
          atomicAdd(out + (size_t)b * TSTEPS + t, s);
        }
      }
    }
  }
}

// ---------------------------------------------------------------------------
extern "C" void kernel_launch(void* const* d_in, const int* in_sizes, int n_in,
                              void* d_out, int out_size, void* d_ws, size_t ws_size,
                              hipStream_t stream) {
  const float* x    = (const float*)d_in[0];
  const float* Wih1 = (const float*)d_in[1];
  const float* Whh1 = (const float*)d_in[2];
  const float* bih1 = (const float*)d_in[3];
  const float* bhh1 = (const float*)d_in[4];
  const float* Wih2 = (const float*)d_in[5];
  const float* Whh2 = (const float*)d_in[6];
  const float* bih2 = (const float*)d_in[7];
  const float* bhh2 = (const float*)d_in[8];
  const float* Wlin = (const float*)d_in[9];
  const float* blin = (const float*)d_in[10];
  float* out = (float*)d_out;
  char* ws = (char*)d_ws;

  init_kernel<<<640, 256, 0, stream>>>(ws, out, blin);
  pack_kernel<<<1536, 256, 0, stream>>>(Whh1, Wih2, Whh2, ws);
  lstm_persist<<<256, 256, 0, stream>>>(x, Wih1, bih1, bhh1, bih2, bhh2, Wlin, out, ws);
}